// Round 8
// baseline (971.123 us; speedup 1.0000x reference)
//
#include <hip/hip_runtime.h>
#include <math.h>

// Problem constants
#define BB 128
#define SS 512
#define NN 32
#define DD 512
#define HH 2
#define MM (BB * NN)          // 4096 rows
#define DSQ (DD * DD)         // 262144
#define NBLK 512u

typedef short bf16x8 __attribute__((ext_vector_type(8)));
typedef float f32x4 __attribute__((ext_vector_type(4)));

__device__ __forceinline__ unsigned short f2bf(float f) {
    unsigned int u = __float_as_uint(f);
    u += 0x7fffu + ((u >> 16) & 1u);
    return (unsigned short)(u >> 16);
}
__device__ __forceinline__ float bf2f(unsigned short h) {
    return __uint_as_float(((unsigned int)h) << 16);
}
__device__ __forceinline__ void g2l16(const void* gp, void* lp) {
    __builtin_amdgcn_global_load_lds(
        (const __attribute__((address_space(1))) void*)gp,
        (__attribute__((address_space(3))) void*)lp, 16, 0, 0);
}

// Software grid barrier: monotonic counter, device-scope atomics, L2 wb/inv
// via __threadfence on both sides. All NBLK blocks co-resident by construction
// (512 blocks, 2/CU hard cap from 64KB LDS + launch_bounds(256,2)).
__device__ __forceinline__ void gridbar(unsigned int* bar) {
    __syncthreads();                       // drains each wave's vmcnt -> L2
    if (threadIdx.x == 0) {
        __threadfence();                   // release: writeback L2
        unsigned int old = atomicAdd(bar, 1u);
        unsigned int target = (old / NBLK + 1u) * NBLK;
        while (atomicAdd(bar, 0u) < target) __builtin_amdgcn_s_sleep(1);
        __threadfence();                   // acquire: invalidate L1/L2
    }
    __syncthreads();
}

// ---------------------------------------------------------------------------
// adj + slot map fused; also zeroes the grid-barrier counter.
// ---------------------------------------------------------------------------
__global__ __launch_bounds__(256) void adj_k(const int* __restrict__ order,
                                             const int* __restrict__ pos,
                                             float* __restrict__ g_gt,
                                             float* __restrict__ g_lt,
                                             int* __restrict__ slot,
                                             unsigned int* __restrict__ bar) {
    int b = blockIdx.x;
    __shared__ int ord[NN];
    __shared__ float sgt[NN][NN + 1];
    __shared__ float slt[NN][NN + 1];
    __shared__ float rs_gt[NN], rs_lt[NN];
    int tid = threadIdx.x;
    if (b == 0 && tid == 0) *bar = 0u;
    slot[b * SS + tid] = -1;
    slot[b * SS + 256 + tid] = -1;
    if (tid < NN) ord[tid] = order[b * NN + tid];
    __syncthreads();
    for (int q = 0; q < 4; ++q) {
        int idx = tid + 256 * q;
        int n = idx >> 5, m = idx & 31;
        bool valid = (ord[n] > 0) && (ord[m] > 0) && (n != m);
        float eye = (n == m) ? 1.f : 0.f;
        bool gt = ord[n] > ord[m];
        sgt[n][m] = ((valid && gt) ? 1.f : 0.f) + eye;
        slt[n][m] = ((valid && !gt) ? 1.f : 0.f) + eye;
    }
    __syncthreads();
    if (tid < NN) {
        float s1 = 0.f, s2 = 0.f;
        for (int m = 0; m < NN; ++m) { s1 += sgt[tid][m]; s2 += slt[tid][m]; }
        rs_gt[tid] = s1; rs_lt[tid] = s2;
    }
    __syncthreads();
    for (int q = 0; q < 4; ++q) {
        int idx = tid + 256 * q;
        int n = idx >> 5, m = idx & 31;
        g_gt[b * 1024 + idx] = sgt[n][m] / rs_gt[n];
        g_lt[b * 1024 + idx] = slt[n][m] / rs_lt[n];
    }
    if (tid < NN) {
        int p = pos[b * NN + tid];
        if (p >= 0) slot[b * SS + p] = tid;
    }
}

// ---------------------------------------------------------------------------
// Weight prep (transpose + bf16) + gate-weight combine.
// ---------------------------------------------------------------------------
struct WSfull { const float* s[12]; int slot[12]; const float* w_g; };

__global__ __launch_bounds__(256) void wprep_k(WSfull w, unsigned short* __restrict__ Wt) {
    int which = blockIdx.x;
    int tile = blockIdx.y;
    int tr = (tile >> 3) * 64, tc = (tile & 7) * 64;
    __shared__ float c1[64][65];
    __shared__ float c2[64][65];
    int lc = threadIdx.x & 63, g4 = threadIdx.x >> 6;
    if (which < 12) {
        const float* src = w.s[which];
        unsigned short* dst = Wt + (size_t)w.slot[which] * DSQ;
        for (int i = 0; i < 16; ++i) {
            int lr = g4 * 16 + i;
            c1[lr][lc] = src[(size_t)(tr + lr) * DD + tc + lc];
        }
        __syncthreads();
        for (int i = 0; i < 16; ++i) {
            int lr = g4 * 16 + i;
            dst[(size_t)(tc + lr) * DD + tr + lc] = f2bf(c1[lc][lr]);
        }
    } else {
        int h = which - 12;
        const float* base = w.w_g + (size_t)h * 4 * DSQ;
        for (int i = 0; i < 16; ++i) {
            int lr = g4 * 16 + i;
            int k = tr + lr, n = tc + lc;
            float a  = base[(size_t)k * DD + n];
            float b2 = base[(size_t)(DD + k) * DD + n];
            float c  = base[(size_t)(2 * DD + k) * DD + n];
            float d4 = base[(size_t)(3 * DD + k) * DD + n];
            c1[lr][lc] = a + c + d4;
            c2[lr][lc] = b2 + c - d4;
        }
        __syncthreads();
        unsigned short* d1 = Wt + (size_t)(h * 8 + 4) * DSQ;
        unsigned short* d2 = Wt + (size_t)(h * 8 + 5) * DSQ;
        for (int i = 0; i < 16; ++i) {
            int lr = g4 * 16 + i;
            d1[(size_t)(tc + lr) * DD + tr + lc] = f2bf(c1[lc][lr]);
            d2[(size_t)(tc + lr) * DD + tr + lc] = f2bf(c2[lc][lr]);
        }
    }
}

// ---------------------------------------------------------------------------
// GEMM tile device function (r6-verified), 64x128 tile, BK=64, dbuf K-loop.
// ---------------------------------------------------------------------------
struct GA {
    const unsigned short* A1; const unsigned short* W1;
    const unsigned short* A2; const unsigned short* W2;
    const float* bias;
    const unsigned short* gin1; const unsigned short* gin2;
    const float* G1; const float* G2;
    unsigned short* out; unsigned short* out2; unsigned short* out3;
};

template <bool DUAL, bool GATE, int EMIX>
__device__ __forceinline__ void gemm_tile(const GA& g, const int bm, const int bn,
                                          char* lds) {
    unsigned short* Ab = (unsigned short*)lds;            // 2 bufs x 4096 shorts
    unsigned short* Bb = (unsigned short*)(lds + 16384);  // 2 bufs x 8192 shorts
    float* gsh = (float*)(lds + 49152);
    const int tid = threadIdx.x;
    const int lane = tid & 63;
    const int wave = tid >> 6;
    const int wr = wave & 1, wc = wave >> 1;

    __syncthreads();   // protect LDS reuse against previous stage

    if (EMIX >= 1) {
        const float4* g1 = (const float4*)(g.G1 + (size_t)(bm >> 5) * 1024);
        ((float4*)gsh)[tid] = g1[tid];
        ((float4*)gsh)[tid + 256] = g1[tid + 256];
        if (EMIX == 2) {
            const float4* g2v = (const float4*)(g.G2 + (size_t)(bm >> 5) * 1024);
            ((float4*)(gsh + 2048))[tid] = g2v[tid];
            ((float4*)(gsh + 2048))[tid + 256] = g2v[tid + 256];
        }
    }

    f32x4 acc[2][4];
#pragma unroll
    for (int i = 0; i < 2; ++i)
#pragma unroll
        for (int j = 0; j < 4; ++j) {
            acc[i][j].x = 0.f; acc[i][j].y = 0.f; acc[i][j].z = 0.f; acc[i][j].w = 0.f;
        }

    const int rA0 = tid >> 3,          sA0 = (tid & 7) ^ (rA0 & 7);
    const int rA1 = (tid + 256) >> 3,  sA1 = (tid & 7) ^ (rA1 & 7);
    int rB[4], sB[4];
#pragma unroll
    for (int q = 0; q < 4; ++q) {
        int e = tid + 256 * q;
        rB[q] = e >> 3;
        sB[q] = (tid & 7) ^ (rB[q] & 7);
    }

    int aoff[2][2], boff[2][4];
#pragma unroll
    for (int t = 0; t < 2; ++t) {
        int sl = t * 4 + (lane >> 4);
        int p = sl ^ (lane & 7);
#pragma unroll
        for (int i = 0; i < 2; ++i) {
            int m = wr * 32 + i * 16 + (lane & 15);
            aoff[t][i] = m * 64 + p * 8;
        }
#pragma unroll
        for (int j = 0; j < 4; ++j) {
            int n = wc * 64 + j * 16 + (lane & 15);
            boff[t][j] = n * 64 + p * 8;
        }
    }

    auto STAGE = [&](int ks, int c) {
        const unsigned short* A = (DUAL && ks >= 8) ? g.A2 : g.A1;
        const unsigned short* W = (DUAL && ks >= 8) ? g.W2 : g.W1;
        const int k0 = (ks & 7) * 64;
        g2l16(A + (size_t)(bm + rA0) * DD + k0 + sA0 * 8, Ab + c * 4096 + tid * 8);
        g2l16(A + (size_t)(bm + rA1) * DD + k0 + sA1 * 8,
              Ab + c * 4096 + (tid + 256) * 8);
#pragma unroll
        for (int q = 0; q < 4; ++q)
            g2l16(W + (size_t)(bn + rB[q]) * DD + k0 + sB[q] * 8,
                  Bb + c * 8192 + (tid + 256 * q) * 8);
    };

    const int NK = DUAL ? 16 : 8;
    STAGE(0, 0);
    __syncthreads();
    int cur = 0;
    for (int ks = 0; ks < NK; ++ks) {
        if (ks + 1 < NK) STAGE(ks + 1, cur ^ 1);
        const unsigned short* Ac = Ab + cur * 4096;
        const unsigned short* Bc = Bb + cur * 8192;
        bf16x8 af[2][2], bf_[2][4];
#pragma unroll
        for (int t = 0; t < 2; ++t) {
#pragma unroll
            for (int i = 0; i < 2; ++i) af[t][i] = *(const bf16x8*)(Ac + aoff[t][i]);
#pragma unroll
            for (int j = 0; j < 4; ++j) bf_[t][j] = *(const bf16x8*)(Bc + boff[t][j]);
        }
#pragma unroll
        for (int t = 0; t < 2; ++t)
#pragma unroll
            for (int i = 0; i < 2; ++i)
#pragma unroll
                for (int j = 0; j < 4; ++j)
                    acc[i][j] = __builtin_amdgcn_mfma_f32_16x16x32_bf16(
                        af[t][i], bf_[t][j], acc[i][j], 0, 0, 0);
        __syncthreads();
        cur ^= 1;
    }

    if (EMIX == 0) {
#pragma unroll
        for (int i = 0; i < 2; ++i) {
            int row = bm + wr * 32 + i * 16 + (lane >> 4) * 4;
#pragma unroll
            for (int j = 0; j < 4; ++j) {
                int col = bn + wc * 64 + j * 16 + (lane & 15);
                float bv = g.bias[col];
#pragma unroll
                for (int rg = 0; rg < 4; ++rg) {
                    float v = acc[i][j][rg] + bv;
                    size_t idx = (size_t)(row + rg) * DD + col;
                    if (GATE) {
                        float gg = 1.f / (1.f + __expf(-v));
                        float x1 = bf2f(g.gin1[idx]);
                        float x2 = bf2f(g.gin2[idx]);
                        g.out[idx] = f2bf(gg * x1 + (1.f - gg) * x2);
                    } else {
                        g.out[idx] = f2bf(fmaxf(v, 0.f));
                    }
                }
            }
        }
    } else {
        float* S = (float*)lds;   // 64x128 fp32 = 32 KB overlays staging bufs
#pragma unroll
        for (int i = 0; i < 2; ++i) {
            int lrow = wr * 32 + i * 16 + (lane >> 4) * 4;
#pragma unroll
            for (int j = 0; j < 4; ++j) {
                int lcol = wc * 64 + j * 16 + (lane & 15);
                float bv = g.bias[bn + lcol];
#pragma unroll
                for (int rg = 0; rg < 4; ++rg) {
                    float v = fmaxf(acc[i][j][rg] + bv, 0.f);
                    S[(lrow + rg) * 128 + lcol] = v;
                    if (EMIX == 2)
                        g.out[(size_t)(bm + lrow + rg) * DD + bn + lcol] = f2bf(v);
                }
            }
        }
        __syncthreads();
        const int ngi = (EMIX == 2) ? 2 : 1;
#pragma unroll
        for (int gi = 0; gi < ngi; ++gi) {
            unsigned short* O = (EMIX == 2) ? (gi ? g.out3 : g.out2) : g.out;
            const float* gb = gsh + gi * 2048;
#pragma unroll
            for (int it = 0; it < 8; ++it) {
                int task = it * 256 + tid;     // 2048: n(64) x dq(32)
                int n = task >> 5, dq = task & 31;
                int bt = n >> 5, nl = n & 31;
                const float* gr = gb + bt * 1024 + nl * 32;
                const float* Sb = S + bt * 32 * 128 + dq * 4;
                f32x4 r = {0.f, 0.f, 0.f, 0.f};
#pragma unroll
                for (int m = 0; m < NN; ++m)
                    r += gr[m] * *(const f32x4*)(Sb + m * 128);
                ushort4 ov;
                ov.x = f2bf(r.x); ov.y = f2bf(r.y); ov.z = f2bf(r.z); ov.w = f2bf(r.w);
                *(ushort4*)(O + (size_t)(bm + n) * DD + bn + dq * 4) = ov;
            }
        }
    }
}

// ---------------------------------------------------------------------------
// Mega-kernel: convmix + 8 GEMM stages + gnn + pmax, software grid barriers.
// 512 blocks x 256 threads, 64KB LDS -> exactly 2 blocks/CU, all co-resident.
// ---------------------------------------------------------------------------
struct MegaA {
    const float* num_enc;
    const float *g_gt, *g_lt;
    unsigned short *node0, *nodeA, *nodeB, *t1, *t2, *ni1, *ni2;
    const unsigned short* Wt;
    const float *b_n1a, *b_n1b, *b_n2a, *b_n2b, *b_g, *b_o;
    const float* enc;
    const int* slot;
    float *out_gnn, *out_nemb, *partial, *out_prob;
    unsigned int* bar;
};

__global__ __launch_bounds__(256, 2) void mega_k(MegaA a) {
    __shared__ __align__(16) char lds[65536];
    const int bid = blockIdx.x;
    const int tid = threadIdx.x;
    const int tile = bid & 255;
    const int bm = (tile >> 2) * 64, bn = (tile & 3) * 128;

    // ---- S0: convmix: node0 = bf16(x); t1 = g_gt@x; t2 = g_lt@x ----
    {
        float* xs = (float*)lds;              // [32][128] 16 KB
        float* gg = (float*)(lds + 16384);    // [2][32][32] 8 KB
        const int b = bid >> 2;
        const int dc = (bid & 3) * 128;
        ((float4*)gg)[tid]       = ((const float4*)(a.g_gt + (size_t)b * 1024))[tid];
        ((float4*)gg)[tid + 256] = ((const float4*)(a.g_lt + (size_t)b * 1024))[tid];
#pragma unroll
        for (int q = 0; q < 4; ++q) {
            int e = tid + 256 * q;
            int row = e >> 5, c4 = (e & 31) * 4;
            float4 v = *(const float4*)(a.num_enc + (size_t)(b * NN + row) * DD + dc + c4);
            *(float4*)&xs[row * 128 + c4] = v;
            ushort4 o;
            o.x = f2bf(v.x); o.y = f2bf(v.y); o.z = f2bf(v.z); o.w = f2bf(v.w);
            *(ushort4*)(a.node0 + (size_t)(b * NN + row) * DD + dc + c4) = o;
        }
        __syncthreads();
#pragma unroll
        for (int gi = 0; gi < 2; ++gi) {
            unsigned short* O = gi ? a.t2 : a.t1;
#pragma unroll
            for (int it = 0; it < 4; ++it) {
                int task = it * 256 + tid;
                int n = task >> 5, dq = task & 31;
                f32x4 r = {0.f, 0.f, 0.f, 0.f};
#pragma unroll
                for (int m = 0; m < NN; ++m)
                    r += gg[gi * 1024 + n * 32 + m] * *(const f32x4*)(&xs[m * 128 + dq * 4]);
                ushort4 ov;
                ov.x = f2bf(r.x); ov.y = f2bf(r.y); ov.z = f2bf(r.z); ov.w = f2bf(r.w);
                *(ushort4*)(O + (size_t)(b * NN + n) * DD + dc + dq * 4) = ov;
            }
        }
    }
    gridbar(a.bar);

    // ---- GEMM chain ----
    for (int h = 0; h < HH; ++h) {
        const unsigned short* Wh = a.Wt + (size_t)h * 8 * DSQ;
        const unsigned short* nodeIn = (h == 0) ? a.node0 : a.nodeA;
        unsigned short* nodeOut = (h == 0) ? a.nodeA : a.nodeB;

        {   // stage A (+mix epilogue): ni = G @ relu(t@Wa + b)
            GA g = {};
            if (bid < 256) {
                g.A1 = a.t1; g.W1 = Wh + 0 * DSQ; g.bias = a.b_n1a + h * DD;
                g.G1 = a.g_gt; g.out = a.ni1;
            } else {
                g.A1 = a.t2; g.W1 = Wh + 2 * DSQ; g.bias = a.b_n2a + h * DD;
                g.G1 = a.g_lt; g.out = a.ni2;
            }
            gemm_tile<false, false, 1>(g, bm, bn, lds);
        }
        gridbar(a.bar);

        {   // stage B: t = relu(ni@Wb + b)
            GA g = {};
            if (bid < 256) {
                g.A1 = a.ni1; g.W1 = Wh + 1 * DSQ; g.bias = a.b_n1b + h * DD;
                g.out = a.t1;
            } else {
                g.A1 = a.ni2; g.W1 = Wh + 3 * DSQ; g.bias = a.b_n2b + h * DD;
                g.out = a.t2;
            }
            gemm_tile<false, false, 0>(g, bm, bn, lds);
        }
        gridbar(a.bar);

        if (bid < 256) {   // gate: info = sigm(t1@Wg1+t2@Wg2+b)*t1 + (1-.)*t2
            GA g = {};
            g.A1 = a.t1; g.W1 = Wh + 4 * DSQ; g.A2 = a.t2; g.W2 = Wh + 5 * DSQ;
            g.bias = a.b_g + h * DD; g.gin1 = a.t1; g.gin2 = a.t2; g.out = a.ni1;
            gemm_tile<true, true, 0>(g, bm, bn, lds);
        }
        gridbar(a.bar);

        if (bid < 256) {   // out: node = relu(x@Wo_a + info@Wo_b + b)
            if (h == 0) {
                GA g = {};
                g.A1 = nodeIn; g.W1 = Wh + 6 * DSQ; g.A2 = a.ni1; g.W2 = Wh + 7 * DSQ;
                g.bias = a.b_o + h * DD;
                g.G1 = a.g_gt; g.G2 = a.g_lt;
                g.out = nodeOut; g.out2 = a.t1; g.out3 = a.t2;
                gemm_tile<true, false, 2>(g, bm, bn, lds);
            } else {
                GA g = {};
                g.A1 = nodeIn; g.W1 = Wh + 6 * DSQ; g.A2 = a.ni1; g.W2 = Wh + 7 * DSQ;
                g.bias = a.b_o + h * DD; g.out = nodeOut;
                gemm_tile<true, false, 0>(g, bm, bn, lds);
            }
        }
        gridbar(a.bar);
    }

    // ---- gnn stage: 2560 units on 512 blocks (5 each) ----
    {
        int* sl = (int*)lds;                  // 32 ints
        float4* red = (float4*)(lds + 256);   // 128 float4
        const unsigned short* node = a.nodeB;
        for (int u = 0; u < 5; ++u) {
            __syncthreads();   // protect sl/red reuse
            int unit = bid * 5 + u;
            int b = unit / 20, y = unit % 20;
            if (y >= 16) {
                int q = y - 16;
                size_t base = (size_t)b * NN * DD + (size_t)q * (NN * DD / 4);
                for (int it = 0; it < 4; ++it) {
                    size_t i = base + (size_t)(it * 256 + tid) * 4;
                    float4 av = *(const float4*)(a.num_enc + i);
                    ushort4 nb = *(const ushort4*)(node + i);
                    float4 r;
                    r.x = av.x + bf2f(nb.x);
                    r.y = av.y + bf2f(nb.y);
                    r.z = av.z + bf2f(nb.z);
                    r.w = av.w + bf2f(nb.w);
                    *(float4*)(a.out_nemb + i) = r;
                }
                continue;
            }
            int s0 = y * 32;
            if (tid < 32) sl[tid] = a.slot[b * SS + s0 + tid];
            __syncthreads();
            const int dv = (tid & 127) * 4;
            const int sh = tid >> 7;
            float4 mx = {-INFINITY, -INFINITY, -INFINITY, -INFINITY};
#pragma unroll 4
            for (int i = 0; i < 16; ++i) {
                int sloc = sh * 16 + i;
                int s = s0 + sloc;
                int n = sl[sloc];
                size_t ebase = ((size_t)s * BB + b) * DD + dv;
                float4 v = *(const float4*)(a.enc + ebase);
                if (n >= 0) {
                    ushort4 nb = *(const ushort4*)(node + ((size_t)b * NN + n) * DD + dv);
                    v.x += bf2f(nb.x);
                    v.y += bf2f(nb.y);
                    v.z += bf2f(nb.z);
                    v.w += bf2f(nb.w);
                }
                *(float4*)(a.out_gnn + ebase) = v;
                mx.x = fmaxf(mx.x, v.x);
                mx.y = fmaxf(mx.y, v.y);
                mx.z = fmaxf(mx.z, v.z);
                mx.w = fmaxf(mx.w, v.w);
            }
            if (sh == 1) red[tid & 127] = mx;
            __syncthreads();
            if (sh == 0) {
                float4 o = red[tid];
                mx.x = fmaxf(mx.x, o.x);
                mx.y = fmaxf(mx.y, o.y);
                mx.z = fmaxf(mx.z, o.z);
                mx.w = fmaxf(mx.w, o.w);
                *(float4*)(a.partial + ((size_t)b * 16 + y) * DD + dv) = mx;
            }
        }
    }
    gridbar(a.bar);

    // ---- pmax: 65536 outputs on 512 blocks (128 each) ----
    if (tid < 128) {
        int i = bid * 128 + tid;
        int b = i >> 9, d = i & 511;
        float m = -INFINITY;
        for (int c = 0; c < 16; ++c)
            m = fmaxf(m, a.partial[((size_t)b * 16 + c) * DD + d]);
        a.out_prob[i] = m;
    }
}

// ---------------------------------------------------------------------------
// Host launch: 3 dispatches total.
// ---------------------------------------------------------------------------
extern "C" void kernel_launch(void* const* d_in, const int* in_sizes, int n_in,
                              void* d_out, int out_size, void* d_ws, size_t ws_size,
                              hipStream_t stream) {
    const float* enc     = (const float*)d_in[0];
    const float* num_enc = (const float*)d_in[1];
    const int*   pos     = (const int*)d_in[2];
    const int*   order   = (const int*)d_in[3];
    const float* w_n1a = (const float*)d_in[4];  const float* b_n1a = (const float*)d_in[5];
    const float* w_n1b = (const float*)d_in[6];  const float* b_n1b = (const float*)d_in[7];
    const float* w_n2a = (const float*)d_in[8];  const float* b_n2a = (const float*)d_in[9];
    const float* w_n2b = (const float*)d_in[10]; const float* b_n2b = (const float*)d_in[11];
    const float* w_g   = (const float*)d_in[12]; const float* b_g   = (const float*)d_in[13];
    const float* w_o   = (const float*)d_in[14]; const float* b_o   = (const float*)d_in[15];

    char* wp = (char*)d_ws;
    float* g_gt = (float*)wp;        wp += (size_t)BB * NN * NN * 4;
    float* g_lt = (float*)wp;        wp += (size_t)BB * NN * NN * 4;
    float* partial = (float*)wp;     wp += (size_t)BB * 16 * DD * 4;
    int* slot = (int*)wp;            wp += (size_t)BB * SS * 4;
    unsigned int* bar = (unsigned int*)wp;       wp += 256;
    unsigned short* Wt = (unsigned short*)wp;    wp += (size_t)16 * DSQ * 2;
    unsigned short* node0 = (unsigned short*)wp; wp += (size_t)MM * DD * 2;
    unsigned short* nodeA = (unsigned short*)wp; wp += (size_t)MM * DD * 2;
    unsigned short* nodeB = (unsigned short*)wp; wp += (size_t)MM * DD * 2;
    unsigned short* ni1 = (unsigned short*)wp;   wp += (size_t)MM * DD * 2;
    unsigned short* ni2 = (unsigned short*)wp;   wp += (size_t)MM * DD * 2;
    unsigned short* t1 = (unsigned short*)wp;    wp += (size_t)MM * DD * 2;
    unsigned short* t2 = (unsigned short*)wp;    wp += (size_t)MM * DD * 2;

    float* out_gnn  = (float*)d_out;
    float* out_nemb = out_gnn + (size_t)SS * BB * DD;
    float* out_prob = out_nemb + (size_t)BB * NN * DD;

    adj_k<<<BB, 256, 0, stream>>>(order, pos, g_gt, g_lt, slot, bar);

    WSfull wsrc;
    const float* srcs[12] = {w_n1a, w_n1b, w_n2a, w_n2b, w_o, w_o + DSQ,
                             w_n1a + DSQ, w_n1b + DSQ, w_n2a + DSQ, w_n2b + DSQ,
                             w_o + 2 * DSQ, w_o + 3 * DSQ};
    int slots[12] = {0, 1, 2, 3, 6, 7, 8, 9, 10, 11, 14, 15};
    for (int i = 0; i < 12; ++i) { wsrc.s[i] = srcs[i]; wsrc.slot[i] = slots[i]; }
    wsrc.w_g = w_g;
    wprep_k<<<dim3(14, 64), 256, 0, stream>>>(wsrc, Wt);

    MegaA ma;
    ma.num_enc = num_enc; ma.g_gt = g_gt; ma.g_lt = g_lt;
    ma.node0 = node0; ma.nodeA = nodeA; ma.nodeB = nodeB;
    ma.t1 = t1; ma.t2 = t2; ma.ni1 = ni1; ma.ni2 = ni2;
    ma.Wt = Wt;
    ma.b_n1a = b_n1a; ma.b_n1b = b_n1b; ma.b_n2a = b_n2a; ma.b_n2b = b_n2b;
    ma.b_g = b_g; ma.b_o = b_o;
    ma.enc = enc; ma.slot = slot;
    ma.out_gnn = out_gnn; ma.out_nemb = out_nemb;
    ma.partial = partial; ma.out_prob = out_prob;
    ma.bar = bar;
    mega_k<<<NBLK, 256, 0, stream>>>(ma);
}